// Round 5
// baseline (254.141 us; speedup 1.0000x reference)
//
#include <hip/hip_runtime.h>
#include <math.h>

#define N_NODES 50000
#define N_EDGES 800000
#define D 64

__device__ __forceinline__ float selu_f(float x) {
    const float scale = 1.0507009873554805f;
    const float alpha = 1.6732632423543772f;
    return x > 0.0f ? scale * x : scale * alpha * expm1f(x);
}

// fp32 -> bf16 bits, round-to-nearest-even
__device__ __forceinline__ unsigned short f2bf(float x) {
    unsigned int u = __float_as_uint(x);
    u += 0x7FFFu + ((u >> 16) & 1u);
    return (unsigned short)(u >> 16);
}

__device__ __forceinline__ float bf2f(unsigned short b) {
    return __uint_as_float((unsigned int)b << 16);
}

// h = feat @ W^T; writes pre = h*skipw + bias (fp32, skip path)
// and hb = bf16(h) (gather copy).
__global__ __launch_bounds__(256) void gemm_kernel(const float* __restrict__ feat,
                                                   const float* __restrict__ W,
                                                   const float* __restrict__ bias,
                                                   const float* __restrict__ skipw,
                                                   unsigned short* __restrict__ hb,
                                                   float* __restrict__ pre) {
    __shared__ float Wt[D][D + 1];  // Wt[k][o] = W[o][k]
    const int tid = threadIdx.x;
    for (int i = tid; i < D * D; i += 256) {
        int o = i >> 6;
        int d = i & 63;
        Wt[d][o] = W[i];
    }
    __syncthreads();

    const int row = blockIdx.x * 4 + (tid >> 6);
    const int col = tid & 63;  // == lane
    if (row >= N_NODES) return;

    // coalesced: lane loads its own element, broadcast via shuffle
    const float f = feat[(size_t)row * D + col];
    float acc = 0.0f;
#pragma unroll
    for (int k = 0; k < D; ++k) {
        acc += __shfl(f, k) * Wt[k][col];
    }

    const size_t idx = (size_t)row * D + col;
    hb[idx] = f2bf(acc);
    pre[idx] = acc * skipw[col] + bias[col];
}

// Build per-dst linked lists: next[e] = old head[dst], head[dst] = e.
__global__ __launch_bounds__(256) void link_kernel(const int* __restrict__ edst,
                                                   int* __restrict__ head,
                                                   int* __restrict__ next) {
    const int e = blockIdx.x * 256 + threadIdx.x;
    if (e >= N_EDGES) return;
    const int dst = edst[e];
    next[e] = atomicExch(&head[dst], e);
}

// One wave per dst node, lane = output dim. Walk the list, gather bf16 rows,
// accumulate fp32, fused epilogue: out = selu(pre + agg).
__global__ __launch_bounds__(256) void agg_epilogue_kernel(const unsigned short* __restrict__ hb,
                                                           const float* __restrict__ pre,
                                                           const int* __restrict__ head,
                                                           const int* __restrict__ next,
                                                           const int* __restrict__ esrc,
                                                           const float* __restrict__ ew,
                                                           float* __restrict__ out) {
    const int gtid = blockIdx.x * 256 + threadIdx.x;
    const int n = gtid >> 6;      // node = wave index
    const int lane = gtid & 63;   // output dim
    if (n >= N_NODES) return;

    float acc = 0.0f;
    int e = head[n];  // wave-uniform
    while (e != -1) {
        const int src = esrc[e];   // uniform
        const float w = ew[e];     // uniform
        const int en = next[e];    // uniform — the only serial dependency
        acc += bf2f(hb[(size_t)src * D + lane]) * w;  // 128 B/wave gather
        e = en;
    }

    const size_t idx = (size_t)n * D + lane;
    out[idx] = selu_f(pre[idx] + acc);
}

extern "C" void kernel_launch(void* const* d_in, const int* in_sizes, int n_in,
                              void* d_out, int out_size, void* d_ws, size_t ws_size,
                              hipStream_t stream) {
    const float* feat  = (const float*)d_in[0];
    const float* W     = (const float*)d_in[1];
    const float* bias  = (const float*)d_in[2];
    const float* skipw = (const float*)d_in[3];
    const float* ew    = (const float*)d_in[4];
    const int*   esrc  = (const int*)d_in[5];
    const int*   edst  = (const int*)d_in[6];
    float* out = (float*)d_out;

    // workspace layout
    float*          pre  = (float*)d_ws;                          // N_NODES*D fp32
    unsigned short* hb   = (unsigned short*)(pre + (size_t)N_NODES * D); // N_NODES*D bf16
    int*            head = (int*)(hb + (size_t)N_NODES * D);      // N_NODES
    int*            next = head + N_NODES;                        // N_EDGES

    // head must start at -1 (ws is poisoned each call); 0xFF bytes == -1
    hipMemsetAsync(head, 0xFF, (size_t)N_NODES * sizeof(int), stream);

    // 1) transform + skip-path precompute + bf16 gather copy
    gemm_kernel<<<(N_NODES + 3) / 4, 256, 0, stream>>>(feat, W, bias, skipw, hb, pre);

    // 2) per-dst linked lists
    link_kernel<<<(N_EDGES + 255) / 256, 256, 0, stream>>>(edst, head, next);

    // 3) segmented reduction via list walk + fused epilogue
    agg_epilogue_kernel<<<(N_NODES * 64 + 255) / 256, 256, 0, stream>>>(
        hb, pre, head, next, esrc, ew, out);
}

// Round 6
// 214.710 us; speedup vs baseline: 1.1836x; 1.1836x over previous
//
#include <hip/hip_runtime.h>
#include <math.h>

#define N_NODES 50000
#define N_EDGES 800000
#define D 64

__device__ __forceinline__ float selu_f(float x) {
    const float scale = 1.0507009873554805f;
    const float alpha = 1.6732632423543772f;
    return x > 0.0f ? scale * x : scale * alpha * expm1f(x);
}

// fp32 -> bf16 bits, round-to-nearest-even
__device__ __forceinline__ unsigned int f2bf(float x) {
    unsigned int u = __float_as_uint(x);
    u += 0x7FFFu + ((u >> 16) & 1u);
    return u >> 16;
}

__device__ __forceinline__ float bf2f(unsigned short b) {
    return __uint_as_float((unsigned int)b << 16);
}

// h = feat @ W^T. Writes pre = h*skipw + bias into `pre` (fp32, = d_out)
// and hb = bf16(h) (gather table).
// Block: 256 thr = 4 waves; 64 rows/block; thread computes 1 row x 16 cols.
__global__ __launch_bounds__(256) void gemm_kernel(const float* __restrict__ feat,
                                                   const float* __restrict__ W,
                                                   const float* __restrict__ bias,
                                                   const float* __restrict__ skipw,
                                                   unsigned short* __restrict__ hb,
                                                   float* __restrict__ pre) {
    __shared__ float Wt[D][68];   // Wt[k][o]; stride 68: 16B-aligned rows, 2-way-max banks
    __shared__ float Sf[64][68];  // staged feature rows
    const int tid = threadIdx.x;
    const int base = blockIdx.x * 64;

    for (int i = tid; i < D * D; i += 256) {
        int o = i >> 6, d = i & 63;
        Wt[d][o] = W[i];
    }
    for (int i = tid; i < 64 * D; i += 256) {
        int r = i >> 6, c = i & 63;
        int row = base + r;
        Sf[r][c] = (row < N_NODES) ? feat[(size_t)row * D + c] : 0.0f;
    }
    __syncthreads();

    const int wv = tid >> 6;
    const int lane = tid & 63;
    const int r = wv * 16 + (lane >> 2);  // row within block
    const int cg = lane & 3;              // col group: cols cg*16 .. cg*16+15
    const int row = base + r;
    if (row >= N_NODES) return;

    float4 a0 = {0, 0, 0, 0}, a1 = {0, 0, 0, 0}, a2 = {0, 0, 0, 0}, a3 = {0, 0, 0, 0};
    const int c0 = cg * 16;
#pragma unroll 4
    for (int k = 0; k < D; ++k) {
        const float f = Sf[r][k];
        const float4 w0 = *(const float4*)&Wt[k][c0 + 0];
        const float4 w1 = *(const float4*)&Wt[k][c0 + 4];
        const float4 w2 = *(const float4*)&Wt[k][c0 + 8];
        const float4 w3 = *(const float4*)&Wt[k][c0 + 12];
        a0.x += f * w0.x; a0.y += f * w0.y; a0.z += f * w0.z; a0.w += f * w0.w;
        a1.x += f * w1.x; a1.y += f * w1.y; a1.z += f * w1.z; a1.w += f * w1.w;
        a2.x += f * w2.x; a2.y += f * w2.y; a2.z += f * w2.z; a2.w += f * w2.w;
        a3.x += f * w3.x; a3.y += f * w3.y; a3.z += f * w3.z; a3.w += f * w3.w;
    }

    const size_t obase = (size_t)row * D + c0;

    // bf16 gather copy: pack 16 values -> two uint4 stores (32B, aligned)
    uint4 p0, p1;
    p0.x = f2bf(a0.x) | (f2bf(a0.y) << 16);
    p0.y = f2bf(a0.z) | (f2bf(a0.w) << 16);
    p0.z = f2bf(a1.x) | (f2bf(a1.y) << 16);
    p0.w = f2bf(a1.z) | (f2bf(a1.w) << 16);
    p1.x = f2bf(a2.x) | (f2bf(a2.y) << 16);
    p1.y = f2bf(a2.z) | (f2bf(a2.w) << 16);
    p1.z = f2bf(a3.x) | (f2bf(a3.y) << 16);
    p1.w = f2bf(a3.z) | (f2bf(a3.w) << 16);
    ((uint4*)(hb + obase))[0] = p0;
    ((uint4*)(hb + obase))[1] = p1;

    // skip path: pre = h*skipw + bias (fp32)
    const float4* sk4 = (const float4*)skipw;
    const float4* b4 = (const float4*)bias;
    float4* pr4 = (float4*)(pre + obase);
    const int g4 = cg * 4;
    float4 s, b, o;
    s = sk4[g4 + 0]; b = b4[g4 + 0];
    o.x = a0.x * s.x + b.x; o.y = a0.y * s.y + b.y; o.z = a0.z * s.z + b.z; o.w = a0.w * s.w + b.w;
    pr4[0] = o;
    s = sk4[g4 + 1]; b = b4[g4 + 1];
    o.x = a1.x * s.x + b.x; o.y = a1.y * s.y + b.y; o.z = a1.z * s.z + b.z; o.w = a1.w * s.w + b.w;
    pr4[1] = o;
    s = sk4[g4 + 2]; b = b4[g4 + 2];
    o.x = a2.x * s.x + b.x; o.y = a2.y * s.y + b.y; o.z = a2.z * s.z + b.z; o.w = a2.w * s.w + b.w;
    pr4[2] = o;
    s = sk4[g4 + 3]; b = b4[g4 + 3];
    o.x = a3.x * s.x + b.x; o.y = a3.y * s.y + b.y; o.z = a3.z * s.z + b.z; o.w = a3.w * s.w + b.w;
    pr4[3] = o;
}

// Build per-dst linked lists: next[e] = old head[dst], head[dst] = e.
__global__ __launch_bounds__(256) void link_kernel(const int* __restrict__ edst,
                                                   int* __restrict__ head,
                                                   int* __restrict__ next) {
    const int e = blockIdx.x * 256 + threadIdx.x;
    if (e >= N_EDGES) return;
    next[e] = atomicExch(&head[edst[e]], e);
}

// Flatten linked lists -> CSR: thread per node, walk chain twice.
// sorted_sw[p] = {src, bits(w)} contiguous per node; nodeinfo[n] = {beg, deg}.
__global__ __launch_bounds__(256) void csr_build_kernel(const int* __restrict__ head,
                                                        const int* __restrict__ next,
                                                        const int* __restrict__ esrc,
                                                        const float* __restrict__ ew,
                                                        int* __restrict__ cursor,
                                                        int2* __restrict__ sorted_sw,
                                                        int2* __restrict__ nodeinfo) {
    const int n = blockIdx.x * 256 + threadIdx.x;
    if (n >= N_NODES) return;

    int deg = 0;
    for (int e = head[n]; e != -1; e = next[e]) deg++;

    const int beg = atomicAdd(cursor, deg);
    nodeinfo[n] = make_int2(beg, deg);

    int p = beg;
    for (int e = head[n]; e != -1; e = next[e]) {
        sorted_sw[p++] = make_int2(esrc[e], __float_as_int(ew[e]));
    }
}

// One wave per dst node, lane = output dim. CSR batches of 64 edges in
// registers, shuffle-broadcast, 4 independent accumulators, fused SELU.
__global__ __launch_bounds__(256) void agg_epilogue_kernel(const unsigned short* __restrict__ hb,
                                                           const int2* __restrict__ nodeinfo,
                                                           const int2* __restrict__ sorted_sw,
                                                           float* __restrict__ out) {
    const int gtid = blockIdx.x * 256 + threadIdx.x;
    const int n = gtid >> 6;
    const int lane = gtid & 63;
    if (n >= N_NODES) return;

    const int2 info = nodeinfo[n];
    const int beg = info.x;
    const int deg = info.y;

    float a0 = 0.f, a1 = 0.f, a2 = 0.f, a3 = 0.f;
    for (int i = 0; i < deg; i += 64) {
        const int cnt = min(64, deg - i);
        int2 sw = make_int2(0, 0);
        if (lane < cnt) sw = sorted_sw[beg + i + lane];

        int j = 0;
        for (; j + 3 < cnt; j += 4) {
            const int s0 = __shfl(sw.x, j + 0);
            const int s1 = __shfl(sw.x, j + 1);
            const int s2 = __shfl(sw.x, j + 2);
            const int s3 = __shfl(sw.x, j + 3);
            const float w0 = __int_as_float(__shfl(sw.y, j + 0));
            const float w1 = __int_as_float(__shfl(sw.y, j + 1));
            const float w2 = __int_as_float(__shfl(sw.y, j + 2));
            const float w3 = __int_as_float(__shfl(sw.y, j + 3));
            const float g0 = bf2f(hb[(size_t)s0 * D + lane]);
            const float g1 = bf2f(hb[(size_t)s1 * D + lane]);
            const float g2 = bf2f(hb[(size_t)s2 * D + lane]);
            const float g3 = bf2f(hb[(size_t)s3 * D + lane]);
            a0 += g0 * w0;
            a1 += g1 * w1;
            a2 += g2 * w2;
            a3 += g3 * w3;
        }
        for (; j < cnt; ++j) {
            const int s = __shfl(sw.x, j);
            const float w = __int_as_float(__shfl(sw.y, j));
            a0 += bf2f(hb[(size_t)s * D + lane]) * w;
        }
    }

    const size_t idx = (size_t)n * D + lane;
    const float pre = out[idx];  // written by gemm_kernel this call
    out[idx] = selu_f(pre + ((a0 + a1) + (a2 + a3)));
}

extern "C" void kernel_launch(void* const* d_in, const int* in_sizes, int n_in,
                              void* d_out, int out_size, void* d_ws, size_t ws_size,
                              hipStream_t stream) {
    const float* feat  = (const float*)d_in[0];
    const float* W     = (const float*)d_in[1];
    const float* bias  = (const float*)d_in[2];
    const float* skipw = (const float*)d_in[3];
    const float* ew    = (const float*)d_in[4];
    const int*   esrc  = (const int*)d_in[5];
    const int*   edst  = (const int*)d_in[6];
    float* out = (float*)d_out;  // doubles as `pre` buffer between gemm and agg

    // workspace layout (alignment-friendly ordering), total ~16.7 MB
    unsigned short* hb        = (unsigned short*)d_ws;               // N_NODES*D bf16
    int2*           sorted_sw = (int2*)(hb + (size_t)N_NODES * D);   // N_EDGES int2
    int2*           nodeinfo  = sorted_sw + N_EDGES;                 // N_NODES int2
    int*            next      = (int*)(nodeinfo + N_NODES);          // N_EDGES
    int*            head      = next + N_EDGES;                      // N_NODES
    int*            cursor    = head + N_NODES;                      // 1

    hipMemsetAsync(head, 0xFF, (size_t)N_NODES * sizeof(int), stream);  // head = -1
    hipMemsetAsync(cursor, 0, sizeof(int), stream);

    // 1) transform + skip-path precompute (into d_out) + bf16 gather table
    gemm_kernel<<<(N_NODES + 63) / 64, 256, 0, stream>>>(feat, W, bias, skipw, hb, out);

    // 2) per-dst linked lists
    link_kernel<<<(N_EDGES + 255) / 256, 256, 0, stream>>>(edst, head, next);

    // 3) linked lists -> CSR (coalesced-per-node writes, no scan cascade)
    csr_build_kernel<<<(N_NODES + 255) / 256, 256, 0, stream>>>(head, next, esrc, ew,
                                                                cursor, sorted_sw, nodeinfo);

    // 4) pipelined segmented reduction + fused SELU epilogue (in-place on d_out)
    agg_epilogue_kernel<<<(N_NODES * 64 + 255) / 256, 256, 0, stream>>>(
        hb, nodeinfo, sorted_sw, out);
}